// Round 4
// baseline (3571.196 us; speedup 1.0000x reference)
//
#include <hip/hip_runtime.h>
#include <math.h>

#define B_  256
#define T_  48
#define D_  89
#define H_  128
#define C_  64
#define NH_ 8
#define HD_ 8
#define N2T 96   // 2*T

// output layout (floats)
#define XIMP_OFF 0
#define LOSS_OFF 1093632
#define HID_OFF  1093633
#define Y_OFF    2666497
#define YS_OFF   2666753

typedef unsigned int uint_t;

__device__ __forceinline__ float wave_sum64(float v) {
    v += __shfl_xor(v, 32);
    v += __shfl_xor(v, 16);
    v += __shfl_xor(v, 8);
    v += __shfl_xor(v, 4);
    v += __shfl_xor(v, 2);
    v += __shfl_xor(v, 1);
    return v;
}

// pack two f32 into bf16x2 (RNE), lo = element 2j, hi = element 2j+1
__device__ __forceinline__ uint_t pack2(float lo, float hi) {
    uint_t a = __float_as_uint(lo), b = __float_as_uint(hi);
    a = (a + 0x7fffu + ((a >> 16) & 1u)) >> 16;
    b = (b + 0x7fffu + ((b >> 16) & 1u)) >> 16;
    return a | (b << 16);
}
__device__ __forceinline__ float blo(uint_t w) { return __uint_as_float(w << 16); }
__device__ __forceinline__ float bhi(uint_t w) { return __uint_as_float(w & 0xffff0000u); }
__device__ __forceinline__ float sigm(float v) { return 1.f / (1.f + __expf(-v)); }

// ---------------- prep: f32 transposes for the transformer-phase kernels only
__device__ __forceinline__ void tr_f32(const float* __restrict__ s, float* __restrict__ d,
                                       int li, int R, int C) {
    int r = li / C, c = li - r * C;
    d[c * R + r] = s[li];
}

__global__ void k_prep(const float* W_wo, const float* W_inp, const float* ain_w,
                       const float* aout_w, const float* ff1_w, const float* ff2_w,
                       const float* W_op1,
                       float* W_woT, float* W_inpT, float* ain_T,
                       float* aout_T, float* ff1_T, float* ff2_T, float* op1_T) {
    int i = blockIdx.x * 256 + threadIdx.x;
    if (i < 7921)         tr_f32(W_wo,   W_woT,  i,          89, 89);
    else if (i < 13617)   tr_f32(W_inp,  W_inpT, i - 7921,   64, 89);
    else if (i < 25905)   tr_f32(ain_w,  ain_T,  i - 13617, 192, 64);
    else if (i < 30001)   tr_f32(aout_w, aout_T, i - 25905,  64, 64);
    else if (i < 34097)   tr_f32(ff1_w,  ff1_T,  i - 30001,  64, 64);
    else if (i < 38193)   tr_f32(ff2_w,  ff2_T,  i - 34097,  64, 64);
    else if (i < 46385)   tr_f32(W_op1,  op1_T,  i - 38193, 128, 64);
}

// ---------------- Phase A: decay factor + time encoder + positional encoding
__global__ void k_phaseA(const float* __restrict__ last_obs,
                         const float* __restrict__ deltas,
                         const float* __restrict__ medians,
                         const float* __restrict__ W_woT, const float* __restrict__ b_wo,
                         const float* __restrict__ W_inpT, const float* __restrict__ b_inp,
                         float* __restrict__ data) {
    int bt = blockIdx.x;
    int b = bt / T_;
    int t = bt - b * T_;
    __shared__ float dd[D_], lo[D_], dec[D_];
    int tid = threadIdx.x;
    int base = (b * T_ + t) * D_;
    if (tid < D_) {
        float dv = deltas[base + tid] - medians[tid];
        dd[tid] = dv;
        lo[tid] = last_obs[base + tid];
    }
    __syncthreads();
    if (tid < D_) {
        float acc = b_wo[tid];
        for (int j = 0; j < D_; ++j) acc = fmaf(dd[j], W_woT[j * D_ + tid], acc);
        float dv = dd[tid];
        float s = (dv > 0.f) ? 1.f : ((dv < 0.f) ? -1.f : 0.f);
        dec[tid] = 0.5f * (1.f - tanhf(s * fabsf(acc)));
    }
    __syncthreads();
    int c = tid & 63;
    int half = tid >> 6;
    const float* src = half ? dec : lo;
    float acc = b_inp[c];
    for (int j = 0; j < D_; ++j) acc = fmaf(src[j], W_inpT[j * C_ + c], acc);
    int i = c >> 1;
    float div = __expf((float)i * -0.28782313662425574f);
    float ang = (float)t * div;
    float pe = (c & 1) ? cosf(ang) : sinf(ang);
    data[((b * N2T) + half * T_ + t) * C_ + c] = acc + pe;
}

// ---------------- qkv: one block per (s,n); 192 threads; writes [n][h][s][d] layout.
__global__ void k_qkv(const float* __restrict__ data,
                      const float* __restrict__ ain_T, const float* __restrict__ ain_b,
                      float* __restrict__ qb, float* __restrict__ kb, float* __restrict__ vb) {
    int bn = blockIdx.x;
    int s = bn / N2T;
    int n = bn - s * N2T;
    __shared__ float row[C_];
    int tid = threadIdx.x;
    if (tid < C_) row[tid] = data[bn * C_ + tid];
    __syncthreads();
    float acc = ain_b[tid];
    for (int j = 0; j < C_; ++j) acc = fmaf(row[j], ain_T[j * 192 + tid], acc);
    int part = tid >> 6;
    int c = tid & 63;
    int h = c >> 3, d = c & 7;
    float* dst = (part == 0) ? qb : ((part == 1) ? kb : vb);
    dst[(((n * NH_ + h) * B_ + s) * HD_) + d] = acc;
}

// ---------------- attention: one block per (n,h); 256 threads (thread = s over B).
__global__ void k_attn(const float* __restrict__ qb, const float* __restrict__ kb,
                       const float* __restrict__ vb, float* __restrict__ attnO) {
    int n = blockIdx.x >> 3;
    int h = blockIdx.x & 7;
    __shared__ float k_lds[B_][HD_ + 1];
    __shared__ float v_lds[B_][HD_ + 1];
    int s = threadIdx.x;
    const float scale = 0.35355339059327373f; // 1/sqrt(8)
    size_t base = ((size_t)blockIdx.x * B_ + s) * HD_;
    float q[HD_];
    #pragma unroll
    for (int d = 0; d < HD_; ++d) q[d] = qb[base + d] * scale;
    #pragma unroll
    for (int d = 0; d < HD_; ++d) { k_lds[s][d] = kb[base + d]; v_lds[s][d] = vb[base + d]; }
    __syncthreads();
    float m = -1e30f;
    for (int t = 0; t < B_; ++t) {
        float sc = 0.f;
        #pragma unroll
        for (int d = 0; d < HD_; ++d) sc = fmaf(q[d], k_lds[t][d], sc);
        m = fmaxf(m, sc);
    }
    float l = 0.f;
    float acc[HD_] = {0.f, 0.f, 0.f, 0.f, 0.f, 0.f, 0.f, 0.f};
    for (int t = 0; t < B_; ++t) {
        float sc = 0.f;
        #pragma unroll
        for (int d = 0; d < HD_; ++d) sc = fmaf(q[d], k_lds[t][d], sc);
        float p = __expf(sc - m);
        l += p;
        #pragma unroll
        for (int d = 0; d < HD_; ++d) acc[d] = fmaf(p, v_lds[t][d], acc[d]);
    }
    float inv = 1.f / l;
    float* op = attnO + ((size_t)s * N2T + n) * C_ + h * HD_;
    #pragma unroll
    for (int d = 0; d < HD_; ++d) op[d] = acc[d] * inv;
}

// ---------------- transformer post-attn (transposed weights, coalesced)
__global__ void k_transform(const float* __restrict__ data,
                            const float* __restrict__ attnO,
                            const float* __restrict__ aout_T, const float* __restrict__ aout_b,
                            const float* __restrict__ ln1_g, const float* __restrict__ ln1_b,
                            const float* __restrict__ ff1_T, const float* __restrict__ ff1_b,
                            const float* __restrict__ ff2_T, const float* __restrict__ ff2_b,
                            const float* __restrict__ ln2_g, const float* __restrict__ ln2_b,
                            const float* __restrict__ op1_T, const float* __restrict__ b_op1,
                            float* __restrict__ val) {
    int bn = blockIdx.x;
    __shared__ float orow[C_], x1s[C_], hbuf[C_], x2s[C_];
    int c = threadIdx.x;
    float d0 = data[bn * C_ + c];
    orow[c] = attnO[bn * C_ + c];
    __syncthreads();
    float acc = aout_b[c];
    for (int j = 0; j < C_; ++j) acc = fmaf(orow[j], aout_T[j * C_ + c], acc);
    float r = d0 + acc;
    float mean = wave_sum64(r) * (1.f / 64.f);
    float df = r - mean;
    float var = wave_sum64(df * df) * (1.f / 64.f);
    float x1 = df * rsqrtf(var + 1e-5f) * ln1_g[c] + ln1_b[c];
    x1s[c] = x1;
    __syncthreads();
    acc = ff1_b[c];
    for (int j = 0; j < C_; ++j) acc = fmaf(x1s[j], ff1_T[j * C_ + c], acc);
    float ge = 0.5f * acc * (1.f + erff(acc * 0.7071067811865475f));
    hbuf[c] = ge;
    __syncthreads();
    acc = ff2_b[c];
    for (int j = 0; j < C_; ++j) acc = fmaf(hbuf[j], ff2_T[j * C_ + c], acc);
    float r2 = x1 + acc;
    float mean2 = wave_sum64(r2) * (1.f / 64.f);
    float df2 = r2 - mean2;
    float var2 = wave_sum64(df2 * df2) * (1.f / 64.f);
    float x2 = df2 * rsqrtf(var2 + 1e-5f) * ln2_g[c] + ln2_b[c];
    x2s[c] = x2;
    __syncthreads();
    #pragma unroll
    for (int rep = 0; rep < 2; ++rep) {
        int k = c + rep * 64;
        float a2 = b_op1[k];
        for (int j = 0; j < C_; ++j) a2 = fmaf(x2s[j], op1_T[j * H_ + k], a2);
        val[(size_t)bn * H_ + k] = a2;
    }
}

// ---------------- h0 = conv1d over n (96 -> 1)
__global__ void k_reduce_h0(const float* __restrict__ val,
                            const float* __restrict__ W_op2, const float* __restrict__ b_op2,
                            float* __restrict__ h0) {
    int b = blockIdx.x;
    int h = threadIdx.x;
    float acc = b_op2[0];
    for (int n = 0; n < N2T; ++n)
        acc = fmaf(val[((size_t)b * N2T + n) * H_ + h], W_op2[n], acc);
    h0[b * H_ + h] = acc;
}

// ---------------- per-step mask denominator
__global__ void k_den(const float* __restrict__ mask, float* __restrict__ den) {
    int t = blockIdx.x;
    int tid = threadIdx.x;
    float s = 0.f;
    const int total = B_ * D_;
    for (int i = tid; i < total; i += 256) {
        int b = i / D_;
        int d = i - b * D_;
        s += mask[(b * T_ + t) * D_ + d];
    }
    s = wave_sum64(s);
    __shared__ float red[4];
    if ((tid & 63) == 0) red[tid >> 6] = s;
    __syncthreads();
    if (tid == 0) den[t] = red[0] + red[1] + red[2] + red[3];
}

// ---------------- recurrent scan: 256 blocks x 512 threads, 1 batch elem/block.
// ALL scan weights live bf16-packed in VGPRs for the whole 48-step loop
// (union array wreg[198], static indices only). Activations in LDS, read as
// wave-uniform float4 broadcasts. No L1/L2 weight traffic in steady state.
// Role map:
//   tid 0..383  : W_ih row tid (89 u), W_hh row tid (64 u)   -> wreg[0..152]
//   tid 0..127  : + W_dh row tid (45 u)                      -> wreg[153..197]
//   tid 384..472: W_hist row (64), W_feat row (45, diag=0), W_wc row (89)
//                 -> wreg[0..197]
__global__ __launch_bounds__(512, 2)
void k_scan(const float* __restrict__ x, const float* __restrict__ mask,
            const float* __restrict__ deltas,
            const float* __restrict__ W_dh, const float* __restrict__ b_dh,
            const float* __restrict__ W_dx, const float* __restrict__ b_dx,
            const float* __restrict__ W_hist, const float* __restrict__ b_hist,
            const float* __restrict__ W_feat, const float* __restrict__ b_feat,
            const float* __restrict__ W_wc, const float* __restrict__ b_wc,
            const float* __restrict__ W_ih, const float* __restrict__ W_hh,
            const float* __restrict__ b_ih, const float* __restrict__ b_hh,
            const float* __restrict__ W_cls, const float* __restrict__ b_cls,
            const float* __restrict__ h0,
            float* __restrict__ out, float* __restrict__ num_part) {
    int b = blockIdx.x;
    int tid = threadIdx.x;

    __shared__ __align__(16) float h_s[H_];
    __shared__ __align__(16) float xt_s[90];
    __shared__ __align__(16) float dt_s[90];
    __shared__ __align__(16) float xr_s[90];
    __shared__ __align__(16) float xh_s[90];
    __shared__ __align__(16) float catg_s[178];   // [ximp(89) | m(89)]
    __shared__ __align__(16) float catb_s[178];   // [gx(89)   | m(89)]
    __shared__ __align__(16) float gis[384], ghs[384];
    __shared__ float diff_s[89];

    uint_t wreg[198];
    float bias0 = 0.f, bias1 = 0.f, bias2 = 0.f, dxw = 0.f, dxb = 0.f;

    if (tid < 384) {
        const float* wi = W_ih + (size_t)tid * 178;
        #pragma unroll
        for (int j = 0; j < 89; ++j) wreg[j] = pack2(wi[2 * j], wi[2 * j + 1]);
        const float* wh = W_hh + (size_t)tid * 128;
        #pragma unroll
        for (int j = 0; j < 64; ++j) wreg[89 + j] = pack2(wh[2 * j], wh[2 * j + 1]);
        bias0 = b_ih[tid];
        bias1 = b_hh[tid];
        if (tid < 128) {
            const float* wd = W_dh + tid * 89;
            #pragma unroll
            for (int j = 0; j < 44; ++j) wreg[153 + j] = pack2(wd[2 * j], wd[2 * j + 1]);
            wreg[197] = pack2(wd[88], 0.f);
            bias2 = b_dh[tid];
            h_s[tid] = h0[b * H_ + tid];
        }
    } else if (tid < 473) {
        int r = tid - 384;
        const float* wh = W_hist + r * 128;
        #pragma unroll
        for (int j = 0; j < 64; ++j) wreg[j] = pack2(wh[2 * j], wh[2 * j + 1]);
        const float* wf = W_feat + r * 89;
        #pragma unroll
        for (int j = 0; j < 44; ++j) {
            float lo = (2 * j == r) ? 0.f : wf[2 * j];
            float hi = (2 * j + 1 == r) ? 0.f : wf[2 * j + 1];
            wreg[64 + j] = pack2(lo, hi);
        }
        wreg[108] = pack2((r == 88) ? 0.f : wf[88], 0.f);
        const float* wc = W_wc + (size_t)r * 178;
        #pragma unroll
        for (int j = 0; j < 89; ++j) wreg[109 + j] = pack2(wc[2 * j], wc[2 * j + 1]);
        bias0 = b_hist[r];
        bias1 = b_feat[r];
        bias2 = b_wc[r];
        dxw = W_dx[r * 90];
        dxb = b_dx[r];
    }
    if (tid == 508) { xr_s[89] = 0.f; dt_s[89] = 0.f; xt_s[89] = 0.f; xh_s[89] = 0.f; }
    // prologue loads (t = 0)
    {
        int base = b * T_ * D_;
        if (tid >= 128 && tid < 217) xt_s[tid - 128] = x[base + tid - 128];
        else if (tid >= 224 && tid < 313) {
            float m = mask[base + tid - 224];
            catg_s[89 + tid - 224] = m;
            catb_s[89 + tid - 224] = m;
        }
        else if (tid >= 320 && tid < 409) dt_s[tid - 320] = deltas[base + tid - 320];
    }
    __syncthreads();

    for (int t = 0; t < T_; ++t) {
        // phase 1: gamma_h decay (threads 0..127)
        if (tid < 128) {
            const float4* d4 = (const float4*)dt_s;
            float a0 = 0.f, a1 = 0.f, a2 = 0.f, a3 = 0.f;
            #pragma unroll
            for (int q = 0; q < 22; ++q) {
                float4 v = d4[q];
                uint_t w0 = wreg[153 + 2 * q], w1 = wreg[154 + 2 * q];
                a0 = fmaf(v.x, blo(w0), a0);
                a1 = fmaf(v.y, bhi(w0), a1);
                a2 = fmaf(v.z, blo(w1), a2);
                a3 = fmaf(v.w, bhi(w1), a3);
            }
            {
                float2 v = ((const float2*)dt_s)[44];
                uint_t w0 = wreg[197];
                a0 = fmaf(v.x, blo(w0), a0);
                a1 = fmaf(v.y, bhi(w0), a1);
            }
            float acc = bias2 + ((a0 + a1) + (a2 + a3));
            h_s[tid] *= __expf(-fmaxf(acc, 0.f));
        }
        __syncthreads();
        // phase 2: x_h, x_r, gamma_x (threads 384..472)
        if (tid >= 384 && tid < 473) {
            int r = tid - 384;
            const float4* h4 = (const float4*)h_s;
            float a0 = 0.f, a1 = 0.f, a2 = 0.f, a3 = 0.f;
            #pragma unroll
            for (int q = 0; q < 32; ++q) {
                float4 v = h4[q];
                uint_t w0 = wreg[2 * q], w1 = wreg[2 * q + 1];
                a0 = fmaf(v.x, blo(w0), a0);
                a1 = fmaf(v.y, bhi(w0), a1);
                a2 = fmaf(v.z, blo(w1), a2);
                a3 = fmaf(v.w, bhi(w1), a3);
            }
            float acc = bias0 + ((a0 + a1) + (a2 + a3));
            xh_s[r] = acc;
            float m = catb_s[89 + r];
            xr_s[r] = m * xt_s[r] + (1.f - m) * acc;
            catb_s[r] = __expf(-fmaxf(dt_s[r] * dxw + dxb, 0.f));
        }
        __syncthreads();
        // phase 3: xu, beta, x_comb, x_imp (threads 384..472)
        if (tid >= 384 && tid < 473) {
            int r = tid - 384;
            const float4* x4 = (const float4*)xr_s;
            float a0 = 0.f, a1 = 0.f, a2 = 0.f, a3 = 0.f;
            #pragma unroll
            for (int q = 0; q < 22; ++q) {
                float4 v = x4[q];
                uint_t w0 = wreg[64 + 2 * q], w1 = wreg[65 + 2 * q];
                a0 = fmaf(v.x, blo(w0), a0);
                a1 = fmaf(v.y, bhi(w0), a1);
                a2 = fmaf(v.z, blo(w1), a2);
                a3 = fmaf(v.w, bhi(w1), a3);
            }
            {
                float2 v = ((const float2*)xr_s)[44];
                uint_t w0 = wreg[108];
                a0 = fmaf(v.x, blo(w0), a0);
                a1 = fmaf(v.y, bhi(w0), a1);
            }
            float xu = bias1 + ((a0 + a1) + (a2 + a3));
            const float4* c4 = (const float4*)catb_s;
            float c0 = 0.f, c1 = 0.f, c2 = 0.f, c3 = 0.f;
            #pragma unroll
            for (int q = 0; q < 44; ++q) {
                float4 v = c4[q];
                uint_t w0 = wreg[109 + 2 * q], w1 = wreg[110 + 2 * q];
                c0 = fmaf(v.x, blo(w0), c0);
                c1 = fmaf(v.y, bhi(w0), c1);
                c2 = fmaf(v.z, blo(w1), c2);
                c3 = fmaf(v.w, bhi(w1), c3);
            }
            {
                float2 v = ((const float2*)catb_s)[88];
                uint_t w0 = wreg[197];
                c0 = fmaf(v.x, blo(w0), c0);
                c1 = fmaf(v.y, bhi(w0), c1);
            }
            float beta = bias2 + ((c0 + c1) + (c2 + c3));
            float xc = beta * xu + (1.f - beta) * xh_s[r];
            float m = catb_s[89 + r];
            float xtv = xt_s[r];
            float xi = m * xtv + (1.f - m) * xc;
            catg_s[r] = xi;
            out[XIMP_OFF + (b * T_ + t) * D_ + r] = xi;
            diff_s[r] = fabsf(xtv - xc) * m;
        }
        __syncthreads();
        // phase 4: gi/gh (threads 0..383) + loss partial (wave 7)
        if (tid < 384) {
            const float4* g4 = (const float4*)catg_s;
            float a0 = 0.f, a1 = 0.f, a2 = 0.f, a3 = 0.f;
            #pragma unroll
            for (int q = 0; q < 44; ++q) {
                float4 v = g4[q];
                uint_t w0 = wreg[2 * q], w1 = wreg[2 * q + 1];
                a0 = fmaf(v.x, blo(w0), a0);
                a1 = fmaf(v.y, bhi(w0), a1);
                a2 = fmaf(v.z, blo(w1), a2);
                a3 = fmaf(v.w, bhi(w1), a3);
            }
            {
                float2 v = ((const float2*)catg_s)[88];
                uint_t w0 = wreg[88];
                a0 = fmaf(v.x, blo(w0), a0);
                a1 = fmaf(v.y, bhi(w0), a1);
            }
            gis[tid] = bias0 + ((a0 + a1) + (a2 + a3));
            const float4* h4 = (const float4*)h_s;
            float c0 = 0.f, c1 = 0.f, c2 = 0.f, c3 = 0.f;
            #pragma unroll
            for (int q = 0; q < 32; ++q) {
                float4 v = h4[q];
                uint_t w0 = wreg[89 + 2 * q], w1 = wreg[90 + 2 * q];
                c0 = fmaf(v.x, blo(w0), c0);
                c1 = fmaf(v.y, bhi(w0), c1);
                c2 = fmaf(v.z, blo(w1), c2);
                c3 = fmaf(v.w, bhi(w1), c3);
            }
            ghs[tid] = bias1 + ((c0 + c1) + (c2 + c3));
        } else if (tid >= 448) {
            int l = tid - 448;
            float s = diff_s[l];
            if (l < 25) s += diff_s[64 + l];
            s = wave_sum64(s);
            if (l == 0) num_part[t * B_ + b] = s;
        }
        __syncthreads();
        // phase 5: GRU update (threads 0..127) + loads for t+1 (threads >=128)
        if (tid < 128) {
            float r = sigm(gis[tid] + ghs[tid]);
            float z = sigm(gis[128 + tid] + ghs[128 + tid]);
            float g = tanhf(gis[256 + tid] + r * ghs[256 + tid]);
            float hn = (1.f - z) * g + z * h_s[tid];
            h_s[tid] = hn;
            out[HID_OFF + (size_t)(b * T_ + t) * H_ + tid] = hn;
        } else if (t + 1 < T_) {
            int base = (b * T_ + t + 1) * D_;
            if (tid < 217) xt_s[tid - 128] = x[base + tid - 128];
            else if (tid >= 224 && tid < 313) {
                float m = mask[base + tid - 224];
                catg_s[89 + tid - 224] = m;
                catb_s[89 + tid - 224] = m;
            }
            else if (tid >= 320 && tid < 409) dt_s[tid - 320] = deltas[base + tid - 320];
        }
        __syncthreads();
    }
    // classifier
    if (tid < 64) {
        float p = h_s[tid] * W_cls[tid] + h_s[tid + 64] * W_cls[tid + 64];
        p = wave_sum64(p);
        if (tid == 0) {
            float y = p + b_cls[0];
            out[Y_OFF + b] = y;
            out[YS_OFF + b] = 1.f / (1.f + __expf(-y));
        }
    }
}

// ---------------- final loss reduction
__global__ void k_loss(const float* __restrict__ num_part, const float* __restrict__ den,
                       float* __restrict__ out) {
    int tid = threadIdx.x;
    float v = 0.f;
    if (tid < T_) {
        float s = 0.f;
        const float* np_ = num_part + tid * B_;
        for (int b = 0; b < B_; ++b) s += np_[b];
        v = s / (den[tid] + 1e-5f);
    }
    v = wave_sum64(v);
    if (tid == 0) out[LOSS_OFF] = v;
}

extern "C" void kernel_launch(void* const* d_in, const int* in_sizes, int n_in,
                              void* d_out, int out_size, void* d_ws, size_t ws_size,
                              hipStream_t stream) {
    const float* x        = (const float*)d_in[0];
    const float* mask     = (const float*)d_in[1];
    const float* deltas   = (const float*)d_in[2];
    const float* last_obs = (const float*)d_in[3];
    const float* medians  = (const float*)d_in[4];
    const float* W_dh  = (const float*)d_in[5];
    const float* b_dh  = (const float*)d_in[6];
    const float* W_dx  = (const float*)d_in[7];
    const float* b_dx  = (const float*)d_in[8];
    const float* W_hist= (const float*)d_in[9];
    const float* b_hist= (const float*)d_in[10];
    const float* W_feat= (const float*)d_in[11];
    const float* b_feat= (const float*)d_in[12];
    const float* W_wc  = (const float*)d_in[13];
    const float* b_wc  = (const float*)d_in[14];
    const float* W_wo  = (const float*)d_in[15];
    const float* b_wo  = (const float*)d_in[16];
    const float* W_cls = (const float*)d_in[17];
    const float* b_cls = (const float*)d_in[18];
    const float* W_ih  = (const float*)d_in[19];
    const float* W_hh  = (const float*)d_in[20];
    const float* b_ih  = (const float*)d_in[21];
    const float* b_hh  = (const float*)d_in[22];
    const float* W_inp = (const float*)d_in[23];
    const float* b_inp = (const float*)d_in[24];
    const float* W_op1 = (const float*)d_in[25];
    const float* b_op1 = (const float*)d_in[26];
    const float* W_op2 = (const float*)d_in[27];
    const float* b_op2 = (const float*)d_in[28];
    const float* attn_in_w  = (const float*)d_in[29];
    const float* attn_in_b  = (const float*)d_in[30];
    const float* attn_out_w = (const float*)d_in[31];
    const float* attn_out_b = (const float*)d_in[32];
    const float* ln1_g = (const float*)d_in[33];
    const float* ln1_b = (const float*)d_in[34];
    const float* ln2_g = (const float*)d_in[35];
    const float* ln2_b = (const float*)d_in[36];
    const float* ff1_w = (const float*)d_in[37];
    const float* ff1_b = (const float*)d_in[38];
    const float* ff2_w = (const float*)d_in[39];
    const float* ff2_b = (const float*)d_in[40];

    float* out = (float*)d_out;
    float* ws = (float*)d_ws;

    float* data  = ws;                                  // B*96*64
    float* qb    = data  + (size_t)B_ * N2T * C_;
    float* kb    = qb    + (size_t)N2T * NH_ * B_ * HD_;
    float* vb    = kb    + (size_t)N2T * NH_ * B_ * HD_;
    float* attnO = vb    + (size_t)N2T * NH_ * B_ * HD_;
    float* val   = attnO + (size_t)B_ * N2T * C_;       // B*96*128
    float* h0    = val   + (size_t)B_ * N2T * H_;
    float* den   = h0    + (size_t)B_ * H_;
    float* nump  = den   + 64;                          // 48*256
    float* W_woT = nump  + T_ * B_;
    float* W_inpT= W_woT + 7921;
    float* ain_T = W_inpT + 5696;
    float* aout_T= ain_T + 12288;
    float* ff1_T = aout_T + 4096;
    float* ff2_T = ff1_T + 4096;
    float* op1_T = ff2_T + 4096;

    k_prep<<<182, 256, 0, stream>>>(W_wo, W_inp, attn_in_w, attn_out_w, ff1_w, ff2_w, W_op1,
                                    W_woT, W_inpT, ain_T, aout_T, ff1_T, ff2_T, op1_T);
    k_phaseA<<<B_ * T_, 128, 0, stream>>>(last_obs, deltas, medians, W_woT, b_wo, W_inpT, b_inp, data);
    k_qkv<<<B_ * N2T, 192, 0, stream>>>(data, ain_T, attn_in_b, qb, kb, vb);
    k_attn<<<N2T * NH_, 256, 0, stream>>>(qb, kb, vb, attnO);
    k_transform<<<B_ * N2T, 64, 0, stream>>>(data, attnO, aout_T, attn_out_b,
                                             ln1_g, ln1_b, ff1_T, ff1_b, ff2_T, ff2_b,
                                             ln2_g, ln2_b, op1_T, b_op1, val);
    k_reduce_h0<<<B_, H_, 0, stream>>>(val, W_op2, b_op2, h0);
    k_den<<<T_, 256, 0, stream>>>(mask, den);
    k_scan<<<B_, 512, 0, stream>>>(x, mask, deltas,
                                   W_dh, b_dh, W_dx, b_dx, W_hist, b_hist, W_feat, b_feat,
                                   W_wc, b_wc, W_ih, W_hh, b_ih, b_hh, W_cls, b_cls,
                                   h0, out, nump);
    k_loss<<<1, 64, 0, stream>>>(nump, den, out);
}

// Round 5
// 2126.687 us; speedup vs baseline: 1.6792x; 1.6792x over previous
//
#include <hip/hip_runtime.h>
#include <math.h>

#define B_  256
#define T_  48
#define D_  89
#define H_  128
#define C_  64
#define NH_ 8
#define HD_ 8
#define N2T 96   // 2*T

// output layout (floats)
#define XIMP_OFF 0
#define LOSS_OFF 1093632
#define HID_OFF  1093633
#define Y_OFF    2666497
#define YS_OFF   2666753

typedef unsigned int uint_t;

__device__ __forceinline__ float wave_sum64(float v) {
    v += __shfl_xor(v, 32);
    v += __shfl_xor(v, 16);
    v += __shfl_xor(v, 8);
    v += __shfl_xor(v, 4);
    v += __shfl_xor(v, 2);
    v += __shfl_xor(v, 1);
    return v;
}

// pack two f32 into bf16x2 (RNE)
__device__ __forceinline__ uint_t pack2(float lo, float hi) {
    uint_t a = __float_as_uint(lo), b = __float_as_uint(hi);
    a = (a + 0x7fffu + ((a >> 16) & 1u)) >> 16;
    b = (b + 0x7fffu + ((b >> 16) & 1u)) >> 16;
    return a | (b << 16);
}
__device__ __forceinline__ float blo(uint_t w) { return __uint_as_float(w << 16); }
__device__ __forceinline__ float bhi(uint_t w) { return __uint_as_float(w & 0xffff0000u); }
__device__ __forceinline__ float sigm(float v) { return 1.f / (1.f + __expf(-v)); }

// 4-fma helper on a float4 against 2 packed uints
#define FMA4(v, w0, w1) do { \
    a0 = fmaf((v).x, blo(w0), a0); \
    a1 = fmaf((v).y, bhi(w0), a1); \
    a0 = fmaf((v).z, blo(w1), a0); \
    a1 = fmaf((v).w, bhi(w1), a1); } while (0)

// ---------------- prep: f32 transposes for the transformer-phase kernels only
__device__ __forceinline__ void tr_f32(const float* __restrict__ s, float* __restrict__ d,
                                       int li, int R, int C) {
    int r = li / C, c = li - r * C;
    d[c * R + r] = s[li];
}

__global__ void k_prep(const float* W_wo, const float* W_inp, const float* ain_w,
                       const float* aout_w, const float* ff1_w, const float* ff2_w,
                       const float* W_op1,
                       float* W_woT, float* W_inpT, float* ain_T,
                       float* aout_T, float* ff1_T, float* ff2_T, float* op1_T) {
    int i = blockIdx.x * 256 + threadIdx.x;
    if (i < 7921)         tr_f32(W_wo,   W_woT,  i,          89, 89);
    else if (i < 13617)   tr_f32(W_inp,  W_inpT, i - 7921,   64, 89);
    else if (i < 25905)   tr_f32(ain_w,  ain_T,  i - 13617, 192, 64);
    else if (i < 30001)   tr_f32(aout_w, aout_T, i - 25905,  64, 64);
    else if (i < 34097)   tr_f32(ff1_w,  ff1_T,  i - 30001,  64, 64);
    else if (i < 38193)   tr_f32(ff2_w,  ff2_T,  i - 34097,  64, 64);
    else if (i < 46385)   tr_f32(W_op1,  op1_T,  i - 38193, 128, 64);
}

// ---------------- Phase A
__global__ void k_phaseA(const float* __restrict__ last_obs,
                         const float* __restrict__ deltas,
                         const float* __restrict__ medians,
                         const float* __restrict__ W_woT, const float* __restrict__ b_wo,
                         const float* __restrict__ W_inpT, const float* __restrict__ b_inp,
                         float* __restrict__ data) {
    int bt = blockIdx.x;
    int b = bt / T_;
    int t = bt - b * T_;
    __shared__ float dd[D_], lo[D_], dec[D_];
    int tid = threadIdx.x;
    int base = (b * T_ + t) * D_;
    if (tid < D_) {
        float dv = deltas[base + tid] - medians[tid];
        dd[tid] = dv;
        lo[tid] = last_obs[base + tid];
    }
    __syncthreads();
    if (tid < D_) {
        float acc = b_wo[tid];
        for (int j = 0; j < D_; ++j) acc = fmaf(dd[j], W_woT[j * D_ + tid], acc);
        float dv = dd[tid];
        float s = (dv > 0.f) ? 1.f : ((dv < 0.f) ? -1.f : 0.f);
        dec[tid] = 0.5f * (1.f - tanhf(s * fabsf(acc)));
    }
    __syncthreads();
    int c = tid & 63;
    int half = tid >> 6;
    const float* src = half ? dec : lo;
    float acc = b_inp[c];
    for (int j = 0; j < D_; ++j) acc = fmaf(src[j], W_inpT[j * C_ + c], acc);
    int i = c >> 1;
    float div = __expf((float)i * -0.28782313662425574f);
    float ang = (float)t * div;
    float pe = (c & 1) ? cosf(ang) : sinf(ang);
    data[((b * N2T) + half * T_ + t) * C_ + c] = acc + pe;
}

// ---------------- qkv
__global__ void k_qkv(const float* __restrict__ data,
                      const float* __restrict__ ain_T, const float* __restrict__ ain_b,
                      float* __restrict__ qb, float* __restrict__ kb, float* __restrict__ vb) {
    int bn = blockIdx.x;
    int s = bn / N2T;
    int n = bn - s * N2T;
    __shared__ float row[C_];
    int tid = threadIdx.x;
    if (tid < C_) row[tid] = data[bn * C_ + tid];
    __syncthreads();
    float acc = ain_b[tid];
    for (int j = 0; j < C_; ++j) acc = fmaf(row[j], ain_T[j * 192 + tid], acc);
    int part = tid >> 6;
    int c = tid & 63;
    int h = c >> 3, d = c & 7;
    float* dst = (part == 0) ? qb : ((part == 1) ? kb : vb);
    dst[(((n * NH_ + h) * B_ + s) * HD_) + d] = acc;
}

// ---------------- attention
__global__ void k_attn(const float* __restrict__ qb, const float* __restrict__ kb,
                       const float* __restrict__ vb, float* __restrict__ attnO) {
    int n = blockIdx.x >> 3;
    int h = blockIdx.x & 7;
    __shared__ float k_lds[B_][HD_ + 1];
    __shared__ float v_lds[B_][HD_ + 1];
    int s = threadIdx.x;
    const float scale = 0.35355339059327373f;
    size_t base = ((size_t)blockIdx.x * B_ + s) * HD_;
    float q[HD_];
    #pragma unroll
    for (int d = 0; d < HD_; ++d) q[d] = qb[base + d] * scale;
    #pragma unroll
    for (int d = 0; d < HD_; ++d) { k_lds[s][d] = kb[base + d]; v_lds[s][d] = vb[base + d]; }
    __syncthreads();
    float m = -1e30f;
    for (int t = 0; t < B_; ++t) {
        float sc = 0.f;
        #pragma unroll
        for (int d = 0; d < HD_; ++d) sc = fmaf(q[d], k_lds[t][d], sc);
        m = fmaxf(m, sc);
    }
    float l = 0.f;
    float acc[HD_] = {0.f, 0.f, 0.f, 0.f, 0.f, 0.f, 0.f, 0.f};
    for (int t = 0; t < B_; ++t) {
        float sc = 0.f;
        #pragma unroll
        for (int d = 0; d < HD_; ++d) sc = fmaf(q[d], k_lds[t][d], sc);
        float p = __expf(sc - m);
        l += p;
        #pragma unroll
        for (int d = 0; d < HD_; ++d) acc[d] = fmaf(p, v_lds[t][d], acc[d]);
    }
    float inv = 1.f / l;
    float* op = attnO + ((size_t)s * N2T + n) * C_ + h * HD_;
    #pragma unroll
    for (int d = 0; d < HD_; ++d) op[d] = acc[d] * inv;
}

// ---------------- transformer post-attn
__global__ void k_transform(const float* __restrict__ data,
                            const float* __restrict__ attnO,
                            const float* __restrict__ aout_T, const float* __restrict__ aout_b,
                            const float* __restrict__ ln1_g, const float* __restrict__ ln1_b,
                            const float* __restrict__ ff1_T, const float* __restrict__ ff1_b,
                            const float* __restrict__ ff2_T, const float* __restrict__ ff2_b,
                            const float* __restrict__ ln2_g, const float* __restrict__ ln2_b,
                            const float* __restrict__ op1_T, const float* __restrict__ b_op1,
                            float* __restrict__ val) {
    int bn = blockIdx.x;
    __shared__ float orow[C_], x1s[C_], hbuf[C_], x2s[C_];
    int c = threadIdx.x;
    float d0 = data[bn * C_ + c];
    orow[c] = attnO[bn * C_ + c];
    __syncthreads();
    float acc = aout_b[c];
    for (int j = 0; j < C_; ++j) acc = fmaf(orow[j], aout_T[j * C_ + c], acc);
    float r = d0 + acc;
    float mean = wave_sum64(r) * (1.f / 64.f);
    float df = r - mean;
    float var = wave_sum64(df * df) * (1.f / 64.f);
    float x1 = df * rsqrtf(var + 1e-5f) * ln1_g[c] + ln1_b[c];
    x1s[c] = x1;
    __syncthreads();
    acc = ff1_b[c];
    for (int j = 0; j < C_; ++j) acc = fmaf(x1s[j], ff1_T[j * C_ + c], acc);
    float ge = 0.5f * acc * (1.f + erff(acc * 0.7071067811865475f));
    hbuf[c] = ge;
    __syncthreads();
    acc = ff2_b[c];
    for (int j = 0; j < C_; ++j) acc = fmaf(hbuf[j], ff2_T[j * C_ + c], acc);
    float r2 = x1 + acc;
    float mean2 = wave_sum64(r2) * (1.f / 64.f);
    float df2 = r2 - mean2;
    float var2 = wave_sum64(df2 * df2) * (1.f / 64.f);
    float x2 = df2 * rsqrtf(var2 + 1e-5f) * ln2_g[c] + ln2_b[c];
    x2s[c] = x2;
    __syncthreads();
    #pragma unroll
    for (int rep = 0; rep < 2; ++rep) {
        int k = c + rep * 64;
        float a2 = b_op1[k];
        for (int j = 0; j < C_; ++j) a2 = fmaf(x2s[j], op1_T[j * H_ + k], a2);
        val[(size_t)bn * H_ + k] = a2;
    }
}

// ---------------- h0 reduce
__global__ void k_reduce_h0(const float* __restrict__ val,
                            const float* __restrict__ W_op2, const float* __restrict__ b_op2,
                            float* __restrict__ h0) {
    int b = blockIdx.x;
    int h = threadIdx.x;
    float acc = b_op2[0];
    for (int n = 0; n < N2T; ++n)
        acc = fmaf(val[((size_t)b * N2T + n) * H_ + h], W_op2[n], acc);
    h0[b * H_ + h] = acc;
}

// ---------------- per-step mask denominator
__global__ void k_den(const float* __restrict__ mask, float* __restrict__ den) {
    int t = blockIdx.x;
    int tid = threadIdx.x;
    float s = 0.f;
    const int total = B_ * D_;
    for (int i = tid; i < total; i += 256) {
        int b = i / D_;
        int d = i - b * D_;
        s += mask[(b * T_ + t) * D_ + d];
    }
    s = wave_sum64(s);
    __shared__ float red[4];
    if ((tid & 63) == 0) red[tid >> 6] = s;
    __syncthreads();
    if (tid == 0) den[t] = red[0] + red[1] + red[2] + red[3];
}

// ---------------- recurrent scan: 256 blocks x 1024 threads, 1 batch elem/block.
// All six scan matrices live bf16-packed in VGPRs, <=101 uints/thread (fits the
// hard 128-VGPR cap of a 16-wave block => no spill, unlike round 4's 198).
// Role map (uints):
//  A 0..383  : W_ih[o] elems 0..87   -> [0..43]; W_hh[o] 0..63  -> [44..75]; tid<89: W_wc q2 -> [76..99]
//  B 384..767: W_ih[o] elems 88..177 -> [0..44]; W_hh[o] 64..127-> [45..76]; r<89: W_wc q3 -> [77..93]
//  C 768..895: W_dh[r] -> [0..44]; r<89: W_hist 64..127 -> [45..76]; W_feat 0..47 -> [77..100]
//  D 896..1023: r<89: W_hist 0..63 -> [0..31]; W_wc q0 -> [32..55]; q1 -> [56..79]; W_feat 48..88 -> [80..100]
__global__ __launch_bounds__(1024)
void k_scan(const float* __restrict__ x, const float* __restrict__ mask,
            const float* __restrict__ deltas,
            const float* __restrict__ W_dh, const float* __restrict__ b_dh,
            const float* __restrict__ W_dx, const float* __restrict__ b_dx,
            const float* __restrict__ W_hist, const float* __restrict__ b_hist,
            const float* __restrict__ W_feat, const float* __restrict__ b_feat,
            const float* __restrict__ W_wc, const float* __restrict__ b_wc,
            const float* __restrict__ W_ih, const float* __restrict__ W_hh,
            const float* __restrict__ b_ih, const float* __restrict__ b_hh,
            const float* __restrict__ W_cls, const float* __restrict__ b_cls,
            const float* __restrict__ h0,
            float* __restrict__ out, float* __restrict__ num_part) {
    int b = blockIdx.x;
    int tid = threadIdx.x;

    __shared__ __align__(16) float h_s[H_];
    __shared__ __align__(16) float xt_s[92];
    __shared__ __align__(16) float dt_s[92];
    __shared__ __align__(16) float xr_s[92];
    __shared__ __align__(16) float xh_s[92];
    __shared__ __align__(16) float catg_s[180];   // [ximp(89) | m(89)]
    __shared__ __align__(16) float catb_s[180];   // [gx(89)   | m(89)]
    __shared__ __align__(16) float gis_p[2][384], ghs_p[2][384];
    __shared__ float p2[2][92], p3xu[2][92], p3b[3][92];
    __shared__ float diff_s[92];

    uint_t wreg[101];
    float bias0 = 0.f, bias1 = 0.f, bias2 = 0.f, dxw = 0.f, dxb = 0.f;

    if (tid < 384) {                       // A
        const float* wi = W_ih + (size_t)tid * 178;
        #pragma unroll
        for (int j = 0; j < 44; ++j) wreg[j] = pack2(wi[2 * j], wi[2 * j + 1]);
        const float* wh = W_hh + (size_t)tid * 128;
        #pragma unroll
        for (int j = 0; j < 32; ++j) wreg[44 + j] = pack2(wh[2 * j], wh[2 * j + 1]);
        bias0 = b_ih[tid];
        bias1 = b_hh[tid];
        if (tid < 89) {
            const float* wc = W_wc + (size_t)tid * 178;
            #pragma unroll
            for (int j = 0; j < 24; ++j) wreg[76 + j] = pack2(wc[96 + 2 * j], wc[97 + 2 * j]);
        }
        if (tid < 128) h_s[tid] = h0[b * H_ + tid];
    } else if (tid < 768) {                // B
        int o = tid - 384;
        const float* wi = W_ih + (size_t)o * 178;
        #pragma unroll
        for (int j = 0; j < 45; ++j) wreg[j] = pack2(wi[88 + 2 * j], wi[89 + 2 * j]);
        const float* wh = W_hh + (size_t)o * 128;
        #pragma unroll
        for (int j = 0; j < 32; ++j) wreg[45 + j] = pack2(wh[64 + 2 * j], wh[65 + 2 * j]);
        if (o < 89) {
            const float* wc = W_wc + (size_t)o * 178;
            #pragma unroll
            for (int j = 0; j < 17; ++j) wreg[77 + j] = pack2(wc[144 + 2 * j], wc[145 + 2 * j]);
        }
    } else if (tid < 896) {                // C
        int r = tid - 768;
        const float* wd = W_dh + r * 89;
        #pragma unroll
        for (int j = 0; j < 44; ++j) wreg[j] = pack2(wd[2 * j], wd[2 * j + 1]);
        wreg[44] = pack2(wd[88], 0.f);
        bias0 = b_dh[r];
        if (r < 89) {
            const float* wh = W_hist + r * 128;
            #pragma unroll
            for (int j = 0; j < 32; ++j) wreg[45 + j] = pack2(wh[64 + 2 * j], wh[65 + 2 * j]);
            const float* wf = W_feat + r * 89;
            #pragma unroll
            for (int j = 0; j < 24; ++j) {
                float lo = (2 * j == r) ? 0.f : wf[2 * j];
                float hi = (2 * j + 1 == r) ? 0.f : wf[2 * j + 1];
                wreg[77 + j] = pack2(lo, hi);
            }
            bias1 = b_feat[r];
            bias2 = b_wc[r];
        }
    } else {                               // D
        int r = tid - 896;
        if (r < 89) {
            const float* wh = W_hist + r * 128;
            #pragma unroll
            for (int j = 0; j < 32; ++j) wreg[j] = pack2(wh[2 * j], wh[2 * j + 1]);
            const float* wc = W_wc + (size_t)r * 178;
            #pragma unroll
            for (int j = 0; j < 24; ++j) wreg[32 + j] = pack2(wc[2 * j], wc[2 * j + 1]);
            #pragma unroll
            for (int j = 0; j < 24; ++j) wreg[56 + j] = pack2(wc[48 + 2 * j], wc[49 + 2 * j]);
            const float* wf = W_feat + r * 89;
            #pragma unroll
            for (int j = 0; j < 20; ++j) {
                float lo = (48 + 2 * j == r) ? 0.f : wf[48 + 2 * j];
                float hi = (49 + 2 * j == r) ? 0.f : wf[49 + 2 * j];
                wreg[80 + j] = pack2(lo, hi);
            }
            wreg[100] = pack2((r == 88) ? 0.f : wf[88], 0.f);
            bias0 = b_hist[r];
            dxw = W_dx[r * 90];
            dxb = b_dx[r];
        }
    }
    // prologue t=0 activations
    {
        int base = b * T_ * D_;
        if (tid >= 128 && tid < 217) xt_s[tid - 128] = x[base + tid - 128];
        else if (tid >= 224 && tid < 313) {
            float m = mask[base + tid - 224];
            catg_s[89 + tid - 224] = m;
            catb_s[89 + tid - 224] = m;
        }
        else if (tid >= 320 && tid < 409) dt_s[tid - 320] = deltas[base + tid - 320];
    }
    __syncthreads();

    for (int t = 0; t < T_; ++t) {
        // ---- P1: gamma_h decay (C, 128 threads)
        if (tid >= 768 && tid < 896) {
            int r = tid - 768;
            const float4* d4 = (const float4*)dt_s;
            float a0 = 0.f, a1 = 0.f;
            #pragma unroll
            for (int q = 0; q < 22; ++q) FMA4(d4[q], wreg[2 * q], wreg[2 * q + 1]);
            a0 = fmaf(dt_s[88], blo(wreg[44]), a0);
            h_s[r] *= __expf(-fmaxf(bias0 + a0 + a1, 0.f));
        }
        __syncthreads();
        // ---- P2a: x_h partials (D: h[0:64], C: h[64:128])
        if (tid >= 896 && tid < 985) {
            int r = tid - 896;
            const float4* h4 = (const float4*)h_s;
            float a0 = 0.f, a1 = 0.f;
            #pragma unroll
            for (int q = 0; q < 16; ++q) FMA4(h4[q], wreg[2 * q], wreg[2 * q + 1]);
            p2[0][r] = a0 + a1;
        } else if (tid >= 768 && tid < 857) {
            int r = tid - 768;
            const float4* h4 = (const float4*)(h_s + 64);
            float a0 = 0.f, a1 = 0.f;
            #pragma unroll
            for (int q = 0; q < 16; ++q) FMA4(h4[q], wreg[45 + 2 * q], wreg[46 + 2 * q]);
            p2[1][r] = a0 + a1;
        }
        __syncthreads();
        // ---- P2b: combine -> xh, xr, gx (D)
        if (tid >= 896 && tid < 985) {
            int r = tid - 896;
            float xh = p2[0][r] + p2[1][r] + bias0;
            xh_s[r] = xh;
            float m = catb_s[89 + r];
            xr_s[r] = m * xt_s[r] + (1.f - m) * xh;
            catb_s[r] = __expf(-fmaxf(dt_s[r] * dxw + dxb, 0.f));
        }
        __syncthreads();
        // ---- P3a: xu + beta partials
        if (tid < 89) {                                   // A: W_wc q2 (catb 96..143)
            const float4* c4 = (const float4*)(catb_s + 96);
            float a0 = 0.f, a1 = 0.f;
            #pragma unroll
            for (int q = 0; q < 12; ++q) FMA4(c4[q], wreg[76 + 2 * q], wreg[77 + 2 * q]);
            p3b[1][tid] = a0 + a1;
        } else if (tid >= 384 && tid < 473) {             // B: W_wc q3 (catb 144..177)
            int r = tid - 384;
            const float4* c4 = (const float4*)(catb_s + 144);
            float a0 = 0.f, a1 = 0.f;
            #pragma unroll
            for (int q = 0; q < 8; ++q) FMA4(c4[q], wreg[77 + 2 * q], wreg[78 + 2 * q]);
            float2 v2 = *(const float2*)(catb_s + 176);
            uint_t w = wreg[93];
            a0 = fmaf(v2.x, blo(w), a0);
            a1 = fmaf(v2.y, bhi(w), a1);
            p3b[2][r] = a0 + a1;
        } else if (tid >= 768 && tid < 857) {             // C: W_feat f0 (xr 0..47)
            int r = tid - 768;
            const float4* x4 = (const float4*)xr_s;
            float a0 = 0.f, a1 = 0.f;
            #pragma unroll
            for (int q = 0; q < 12; ++q) FMA4(x4[q], wreg[77 + 2 * q], wreg[78 + 2 * q]);
            p3xu[0][r] = a0 + a1;
        } else if (tid >= 896 && tid < 985) {             // D: W_feat f1 + W_wc q0+q1
            int r = tid - 896;
            const float4* x4 = (const float4*)(xr_s + 48);
            float a0 = 0.f, a1 = 0.f;
            #pragma unroll
            for (int q = 0; q < 10; ++q) FMA4(x4[q], wreg[80 + 2 * q], wreg[81 + 2 * q]);
            a0 = fmaf(xr_s[88], blo(wreg[100]), a0);
            p3xu[1][r] = a0 + a1;
            const float4* c4 = (const float4*)catb_s;
            a0 = 0.f; a1 = 0.f;
            #pragma unroll
            for (int q = 0; q < 12; ++q) FMA4(c4[q], wreg[32 + 2 * q], wreg[33 + 2 * q]);
            const float4* c4b = (const float4*)(catb_s + 48);
            #pragma unroll
            for (int q = 0; q < 12; ++q) FMA4(c4b[q], wreg[56 + 2 * q], wreg[57 + 2 * q]);
            p3b[0][r] = a0 + a1;
        }
        __syncthreads();
        // ---- P3b: combine -> x_comb, x_imp, diff (C)
        if (tid >= 768 && tid < 857) {
            int r = tid - 768;
            float xu = p3xu[0][r] + p3xu[1][r] + bias1;
            float beta = p3b[0][r] + p3b[1][r] + p3b[2][r] + bias2;
            float xc = beta * xu + (1.f - beta) * xh_s[r];
            float m = catb_s[89 + r];
            float xtv = xt_s[r];
            float xi = m * xtv + (1.f - m) * xc;
            catg_s[r] = xi;
            out[XIMP_OFF + (b * T_ + t) * D_ + r] = xi;
            diff_s[r] = fabsf(xtv - xc) * m;
        }
        __syncthreads();
        // ---- P4: gi/gh partials (A,B) + loss reduce (wave 15) + next-t loads (C, D w14)
        if (tid < 384) {
            const float4* g4 = (const float4*)catg_s;
            float a0 = 0.f, a1 = 0.f;
            #pragma unroll
            for (int q = 0; q < 22; ++q) FMA4(g4[q], wreg[2 * q], wreg[2 * q + 1]);
            gis_p[0][tid] = a0 + a1 + bias0;
            const float4* h4 = (const float4*)h_s;
            a0 = 0.f; a1 = 0.f;
            #pragma unroll
            for (int q = 0; q < 16; ++q) FMA4(h4[q], wreg[44 + 2 * q], wreg[45 + 2 * q]);
            ghs_p[0][tid] = a0 + a1 + bias1;
        } else if (tid < 768) {
            int o = tid - 384;
            const float4* g4 = (const float4*)(catg_s + 88);
            float a0 = 0.f, a1 = 0.f;
            #pragma unroll
            for (int q = 0; q < 22; ++q) FMA4(g4[q], wreg[2 * q], wreg[2 * q + 1]);
            float2 v2 = *(const float2*)(catg_s + 176);
            uint_t w = wreg[44];
            a0 = fmaf(v2.x, blo(w), a0);
            a1 = fmaf(v2.y, bhi(w), a1);
            gis_p[1][o] = a0 + a1;
            const float4* h4 = (const float4*)(h_s + 64);
            a0 = 0.f; a1 = 0.f;
            #pragma unroll
            for (int q = 0; q < 16; ++q) FMA4(h4[q], wreg[45 + 2 * q], wreg[46 + 2 * q]);
            ghs_p[1][o] = a0 + a1;
        } else if (tid >= 960) {
            int l = tid - 960;
            float s = diff_s[l];
            if (l < 25) s += diff_s[64 + l];
            s = wave_sum64(s);
            if (l == 0) num_part[t * B_ + b] = s;
        } else if (t + 1 < T_) {
            int base = (b * T_ + t + 1) * D_;
            if (tid < 896) {               // C: next xt + dt
                int r = tid - 768;
                if (r < 89) { xt_s[r] = x[base + r]; dt_s[r] = deltas[base + r]; }
            } else {                       // D wave 14: next m -> catb half
                int l = tid - 896;
                catb_s[89 + l] = mask[base + l];
                if (l < 25) catb_s[89 + 64 + l] = mask[base + 64 + l];
            }
        }
        __syncthreads();
        // ---- P5: GRU update + copy next-m into catg half
        if (tid < 128) {
            float r = sigm(gis_p[0][tid] + gis_p[1][tid] + ghs_p[0][tid] + ghs_p[1][tid]);
            float z = sigm(gis_p[0][128 + tid] + gis_p[1][128 + tid] +
                           ghs_p[0][128 + tid] + ghs_p[1][128 + tid]);
            float g = tanhf(gis_p[0][256 + tid] + gis_p[1][256 + tid] +
                            r * (ghs_p[0][256 + tid] + ghs_p[1][256 + tid]));
            float hn = (1.f - z) * g + z * h_s[tid];
            h_s[tid] = hn;
            out[HID_OFF + (size_t)(b * T_ + t) * H_ + tid] = hn;
        } else if (tid >= 128 && tid < 217 && t + 1 < T_) {
            int l = tid - 128;
            catg_s[89 + l] = catb_s[89 + l];
        }
        __syncthreads();
    }
    // classifier
    if (tid < 64) {
        float p = h_s[tid] * W_cls[tid] + h_s[tid + 64] * W_cls[tid + 64];
        p = wave_sum64(p);
        if (tid == 0) {
            float y = p + b_cls[0];
            out[Y_OFF + b] = y;
            out[YS_OFF + b] = 1.f / (1.f + __expf(-y));
        }
    }
}

// ---------------- final loss reduction
__global__ void k_loss(const float* __restrict__ num_part, const float* __restrict__ den,
                       float* __restrict__ out) {
    int tid = threadIdx.x;
    float v = 0.f;
    if (tid < T_) {
        float s = 0.f;
        const float* np_ = num_part + tid * B_;
        for (int b = 0; b < B_; ++b) s += np_[b];
        v = s / (den[tid] + 1e-5f);
    }
    v = wave_sum64(v);
    if (tid == 0) out[LOSS_OFF] = v;
}

extern "C" void kernel_launch(void* const* d_in, const int* in_sizes, int n_in,
                              void* d_out, int out_size, void* d_ws, size_t ws_size,
                              hipStream_t stream) {
    const float* x        = (const float*)d_in[0];
    const float* mask     = (const float*)d_in[1];
    const float* deltas   = (const float*)d_in[2];
    const float* last_obs = (const float*)d_in[3];
    const float* medians  = (const float*)d_in[4];
    const float* W_dh  = (const float*)d_in[5];
    const float* b_dh  = (const float*)d_in[6];
    const float* W_dx  = (const float*)d_in[7];
    const float* b_dx  = (const float*)d_in[8];
    const float* W_hist= (const float*)d_in[9];
    const float* b_hist= (const float*)d_in[10];
    const float* W_feat= (const float*)d_in[11];
    const float* b_feat= (const float*)d_in[12];
    const float* W_wc  = (const float*)d_in[13];
    const float* b_wc  = (const float*)d_in[14];
    const float* W_wo  = (const float*)d_in[15];
    const float* b_wo  = (const float*)d_in[16];
    const float* W_cls = (const float*)d_in[17];
    const float* b_cls = (const float*)d_in[18];
    const float* W_ih  = (const float*)d_in[19];
    const float* W_hh  = (const float*)d_in[20];
    const float* b_ih  = (const float*)d_in[21];
    const float* b_hh  = (const float*)d_in[22];
    const float* W_inp = (const float*)d_in[23];
    const float* b_inp = (const float*)d_in[24];
    const float* W_op1 = (const float*)d_in[25];
    const float* b_op1 = (const float*)d_in[26];
    const float* W_op2 = (const float*)d_in[27];
    const float* b_op2 = (const float*)d_in[28];
    const float* attn_in_w  = (const float*)d_in[29];
    const float* attn_in_b  = (const float*)d_in[30];
    const float* attn_out_w = (const float*)d_in[31];
    const float* attn_out_b = (const float*)d_in[32];
    const float* ln1_g = (const float*)d_in[33];
    const float* ln1_b = (const float*)d_in[34];
    const float* ln2_g = (const float*)d_in[35];
    const float* ln2_b = (const float*)d_in[36];
    const float* ff1_w = (const float*)d_in[37];
    const float* ff1_b = (const float*)d_in[38];
    const float* ff2_w = (const float*)d_in[39];
    const float* ff2_b = (const float*)d_in[40];

    float* out = (float*)d_out;
    float* ws = (float*)d_ws;

    float* data  = ws;
    float* qb    = data  + (size_t)B_ * N2T * C_;
    float* kb    = qb    + (size_t)N2T * NH_ * B_ * HD_;
    float* vb    = kb    + (size_t)N2T * NH_ * B_ * HD_;
    float* attnO = vb    + (size_t)N2T * NH_ * B_ * HD_;
    float* val   = attnO + (size_t)B_ * N2T * C_;
    float* h0    = val   + (size_t)B_ * N2T * H_;
    float* den   = h0    + (size_t)B_ * H_;
    float* nump  = den   + 64;
    float* W_woT = nump  + T_ * B_;
    float* W_inpT= W_woT + 7921;
    float* ain_T = W_inpT + 5696;
    float* aout_T= ain_T + 12288;
    float* ff1_T = aout_T + 4096;
    float* ff2_T = ff1_T + 4096;
    float* op1_T = ff2_T + 4096;

    k_prep<<<182, 256, 0, stream>>>(W_wo, W_inp, attn_in_w, attn_out_w, ff1_w, ff2_w, W_op1,
                                    W_woT, W_inpT, ain_T, aout_T, ff1_T, ff2_T, op1_T);
    k_phaseA<<<B_ * T_, 128, 0, stream>>>(last_obs, deltas, medians, W_woT, b_wo, W_inpT, b_inp, data);
    k_qkv<<<B_ * N2T, 192, 0, stream>>>(data, ain_T, attn_in_b, qb, kb, vb);
    k_attn<<<N2T * NH_, 256, 0, stream>>>(qb, kb, vb, attnO);
    k_transform<<<B_ * N2T, 64, 0, stream>>>(data, attnO, aout_T, attn_out_b,
                                             ln1_g, ln1_b, ff1_T, ff1_b, ff2_T, ff2_b,
                                             ln2_g, ln2_b, op1_T, b_op1, val);
    k_reduce_h0<<<B_, H_, 0, stream>>>(val, W_op2, b_op2, h0);
    k_den<<<T_, 256, 0, stream>>>(mask, den);
    k_scan<<<B_, 1024, 0, stream>>>(x, mask, deltas,
                                    W_dh, b_dh, W_dx, b_dx, W_hist, b_hist, W_feat, b_feat,
                                    W_wc, b_wc, W_ih, W_hh, b_ih, b_hh, W_cls, b_cls,
                                    h0, out, nump);
    k_loss<<<1, 64, 0, stream>>>(nump, den, out);
}